// Round 2
// baseline (117.353 us; speedup 1.0000x reference)
//
#include <hip/hip_runtime.h>

// LIF: v = v*0.5 + x_t; s = (v >= 1); v -= s   (DECAY=0.5 exact in fp32 -> bit-exact vs ref)
// x: (N=16, T=64, C=256, H=16, W=16) fp32 ; v_init: (N, C, H, W) fp32
// out: spikes (N, T, C, H, W) fp32

constexpr int T_STEPS = 64;
constexpr int SPATIAL = 256 * 16 * 16;   // C*H*W floats per (n,t) slice
constexpr int SPAT4   = SPATIAL / 4;     // 16384 float4 per slice
constexpr int N_BATCH = 16;
constexpr int TB      = 4;               // t-steps per load/store burst
constexpr int NT      = T_STEPS / TB;    // 16 bursts

// Force <=64 VGPR: 8 waves/SIMD = 32 waves/CU (occupancy cliff at 64).
__global__ __launch_bounds__(256, 8)
void lif_kernel(const float4* __restrict__ x,
                const float4* __restrict__ v_init,
                float4* __restrict__ out)
{
    const int gid = blockIdx.x * blockDim.x + threadIdx.x;  // float4 idx over (N, SPAT4)
    const int n   = gid >> 14;             // / 16384
    const int s4  = gid & (SPAT4 - 1);

    const int nbase = n * (T_STEPS * SPAT4);   // float4 units; max 16.7M fits int32
    const float4* __restrict__ xp = x   + nbase + s4;
    float4*       __restrict__ op = out + nbase + s4;

    float4 v = v_init[n * SPAT4 + s4];

    #pragma unroll
    for (int tb = 0; tb < NT; ++tb) {
        float4 b[TB];
        // burst-load TB slices (independent addresses -> deep vmcnt pipeline)
        #pragma unroll
        for (int k = 0; k < TB; ++k)
            b[k] = xp[(tb * TB + k) * SPAT4];

        // serial v-recurrence; overwrite b[k] with the spike (no extra regs)
        #pragma unroll
        for (int k = 0; k < TB; ++k) {
            float sx, sy, sz, sw;
            v.x = v.x * 0.5f + b[k].x;  sx = (v.x >= 1.0f) ? 1.0f : 0.0f;  v.x -= sx;
            v.y = v.y * 0.5f + b[k].y;  sy = (v.y >= 1.0f) ? 1.0f : 0.0f;  v.y -= sy;
            v.z = v.z * 0.5f + b[k].z;  sz = (v.z >= 1.0f) ? 1.0f : 0.0f;  v.z -= sz;
            v.w = v.w * 0.5f + b[k].w;  sw = (v.w >= 1.0f) ? 1.0f : 0.0f;  v.w -= sw;
            b[k].x = sx; b[k].y = sy; b[k].z = sz; b[k].w = sw;
        }

        // burst-store TB slices
        #pragma unroll
        for (int k = 0; k < TB; ++k)
            op[(tb * TB + k) * SPAT4] = b[k];
    }
}

extern "C" void kernel_launch(void* const* d_in, const int* in_sizes, int n_in,
                              void* d_out, int out_size, void* d_ws, size_t ws_size,
                              hipStream_t stream)
{
    const float4* x      = (const float4*)d_in[0];
    const float4* v_init = (const float4*)d_in[1];
    float4*       out    = (float4*)d_out;

    const int total4 = N_BATCH * SPAT4;     // 262144 threads
    const int block  = 256;
    const int grid   = total4 / block;      // 1024 blocks

    lif_kernel<<<grid, block, 0, stream>>>(x, v_init, out);
}

// Round 3
// 85.873 us; speedup vs baseline: 1.3666x; 1.3666x over previous
//
#include <hip/hip_runtime.h>

// LIF: v = v*0.5 + x_t; s = (v >= 1); v -= s   (DECAY=0.5 exact in fp32 -> bit-exact vs ref)
// x: (N=16, T=64, C=256, H=16, W=16) fp32 ; v_init: (N, C, H, W) fp32
// out: spikes (N, T, C, H, W) fp32
//
// R3 experiment: nontemporal stores for the spike output so the 256 MB write
// stream does not evict x (256 MB == L3 capacity) from Infinity Cache across
// graph replays. Loads of x stay default (cache-allocating).

typedef float f32x4 __attribute__((ext_vector_type(4)));

constexpr int T_STEPS = 64;
constexpr int SPATIAL = 256 * 16 * 16;   // C*H*W floats per (n,t) slice
constexpr int SPAT4   = SPATIAL / 4;     // 16384 float4 per slice
constexpr int N_BATCH = 16;
constexpr int TB      = 4;               // t-steps per load/store burst
constexpr int NT      = T_STEPS / TB;    // 16 bursts

__global__ __launch_bounds__(256, 8)
void lif_kernel(const f32x4* __restrict__ x,
                const f32x4* __restrict__ v_init,
                f32x4* __restrict__ out)
{
    const int gid = blockIdx.x * blockDim.x + threadIdx.x;  // float4 idx over (N, SPAT4)
    const int n   = gid >> 14;             // / 16384
    const int s4  = gid & (SPAT4 - 1);

    const int nbase = n * (T_STEPS * SPAT4);   // float4 units; max 16.7M fits int32
    const f32x4* __restrict__ xp = x   + nbase + s4;
    f32x4*       __restrict__ op = out + nbase + s4;

    f32x4 v = v_init[n * SPAT4 + s4];

    #pragma unroll
    for (int tb = 0; tb < NT; ++tb) {
        f32x4 b[TB];
        // burst-load TB slices (independent addresses -> deep vmcnt pipeline)
        #pragma unroll
        for (int k = 0; k < TB; ++k)
            b[k] = xp[(tb * TB + k) * SPAT4];

        // serial v-recurrence; overwrite b[k] with the spike (no extra regs)
        #pragma unroll
        for (int k = 0; k < TB; ++k) {
            f32x4 s;
            v.x = v.x * 0.5f + b[k].x;  s.x = (v.x >= 1.0f) ? 1.0f : 0.0f;  v.x -= s.x;
            v.y = v.y * 0.5f + b[k].y;  s.y = (v.y >= 1.0f) ? 1.0f : 0.0f;  v.y -= s.y;
            v.z = v.z * 0.5f + b[k].z;  s.z = (v.z >= 1.0f) ? 1.0f : 0.0f;  v.z -= s.z;
            v.w = v.w * 0.5f + b[k].w;  s.w = (v.w >= 1.0f) ? 1.0f : 0.0f;  v.w -= s.w;
            b[k] = s;
        }

        // burst-store TB slices, nontemporal (bypass/low-priority cache alloc)
        #pragma unroll
        for (int k = 0; k < TB; ++k)
            __builtin_nontemporal_store(b[k], &op[(tb * TB + k) * SPAT4]);
    }
}

extern "C" void kernel_launch(void* const* d_in, const int* in_sizes, int n_in,
                              void* d_out, int out_size, void* d_ws, size_t ws_size,
                              hipStream_t stream)
{
    const f32x4* x      = (const f32x4*)d_in[0];
    const f32x4* v_init = (const f32x4*)d_in[1];
    f32x4*       out    = (f32x4*)d_out;

    const int total4 = N_BATCH * SPAT4;     // 262144 threads
    const int block  = 256;
    const int grid   = total4 / block;      // 1024 blocks

    lif_kernel<<<grid, block, 0, stream>>>(x, v_init, out);
}

// Round 4
// 84.711 us; speedup vs baseline: 1.3853x; 1.0137x over previous
//
#include <hip/hip_runtime.h>

// LIF: v = v*0.5 + x_t; s = (v >= 1); v -= s   (DECAY=0.5 exact in fp32 -> bit-exact vs ref)
// x: (N=16, T=64, C=256, H=16, W=16) fp32 ; v_init: (N, C, H, W) fp32
// out: spikes (N, T, C, H, W) fp32
//
// R3 (kept): nontemporal stores -> write stream doesn't evict x from the
// 256 MB Infinity Cache across graph replays (FETCH 260->133 MB, -27% time).
// R4 experiment: burst depth TB 4->8 to double per-wave outstanding reads
// (stores depend on loads through the v-chain; deeper bursts = fewer drain
// points, more memory-level parallelism). ~46 VGPR, still <=64 (8 waves/SIMD).

typedef float f32x4 __attribute__((ext_vector_type(4)));

constexpr int T_STEPS = 64;
constexpr int SPATIAL = 256 * 16 * 16;   // C*H*W floats per (n,t) slice
constexpr int SPAT4   = SPATIAL / 4;     // 16384 float4 per slice
constexpr int N_BATCH = 16;
constexpr int TB      = 8;               // t-steps per load/store burst
constexpr int NT      = T_STEPS / TB;    // 8 bursts

__global__ __launch_bounds__(256, 8)
void lif_kernel(const f32x4* __restrict__ x,
                const f32x4* __restrict__ v_init,
                f32x4* __restrict__ out)
{
    const int gid = blockIdx.x * blockDim.x + threadIdx.x;  // float4 idx over (N, SPAT4)
    const int n   = gid >> 14;             // / 16384
    const int s4  = gid & (SPAT4 - 1);

    const int nbase = n * (T_STEPS * SPAT4);   // float4 units; max 16.7M fits int32
    const f32x4* __restrict__ xp = x   + nbase + s4;
    f32x4*       __restrict__ op = out + nbase + s4;

    f32x4 v = v_init[n * SPAT4 + s4];

    #pragma unroll
    for (int tb = 0; tb < NT; ++tb) {
        f32x4 b[TB];
        // burst-load TB slices (independent addresses -> deep vmcnt pipeline)
        #pragma unroll
        for (int k = 0; k < TB; ++k)
            b[k] = xp[(tb * TB + k) * SPAT4];

        // serial v-recurrence; overwrite b[k] with the spike (no extra regs)
        #pragma unroll
        for (int k = 0; k < TB; ++k) {
            f32x4 s;
            v.x = v.x * 0.5f + b[k].x;  s.x = (v.x >= 1.0f) ? 1.0f : 0.0f;  v.x -= s.x;
            v.y = v.y * 0.5f + b[k].y;  s.y = (v.y >= 1.0f) ? 1.0f : 0.0f;  v.y -= s.y;
            v.z = v.z * 0.5f + b[k].z;  s.z = (v.z >= 1.0f) ? 1.0f : 0.0f;  v.z -= s.z;
            v.w = v.w * 0.5f + b[k].w;  s.w = (v.w >= 1.0f) ? 1.0f : 0.0f;  v.w -= s.w;
            b[k] = s;
        }

        // burst-store TB slices, nontemporal (don't allocate in L2/L3)
        #pragma unroll
        for (int k = 0; k < TB; ++k)
            __builtin_nontemporal_store(b[k], &op[(tb * TB + k) * SPAT4]);
    }
}

extern "C" void kernel_launch(void* const* d_in, const int* in_sizes, int n_in,
                              void* d_out, int out_size, void* d_ws, size_t ws_size,
                              hipStream_t stream)
{
    const f32x4* x      = (const f32x4*)d_in[0];
    const f32x4* v_init = (const f32x4*)d_in[1];
    f32x4*       out    = (f32x4*)d_out;

    const int total4 = N_BATCH * SPAT4;     // 262144 threads
    const int block  = 256;
    const int grid   = total4 / block;      // 1024 blocks

    lif_kernel<<<grid, block, 0, stream>>>(x, v_init, out);
}